// Round 1
// 205.910 us; speedup vs baseline: 1.0091x; 1.0091x over previous
//
#include <hip/hip_runtime.h>
#include <cstdint>

#define DEV __device__ __forceinline__

typedef __bf16 bf16x4 __attribute__((ext_vector_type(4)));
typedef __bf16 bf16x8 __attribute__((ext_vector_type(8)));
typedef float  floatx4 __attribute__((ext_vector_type(4)));
typedef short  short4v __attribute__((ext_vector_type(4)));

constexpr int BB = 8, NSEQ = 1024, DMODEL = 768, NH = 12, HD = 64;
constexpr int MTOK = BB * NSEQ;   // 8192 tokens
constexpr int NQKV = 3 * DMODEL;  // 2304
constexpr float CS = 0.18033688011112042f;  // (1/sqrt(64)) * log2(e), folded into Q

DEV void async_copy16(void* lds, const void* g) {
    // global -> LDS direct copy, 16B/lane. LDS dest must be wave-base + lane*16.
    __builtin_amdgcn_global_load_lds(
        (__attribute__((address_space(1))) void*)(const_cast<void*>(g)),
        (__attribute__((address_space(3))) void*)lds,
        16, 0, 0);
}

DEV floatx4 mfma16x32(bf16x8 a, bf16x8 b, floatx4 c) {
    return __builtin_amdgcn_mfma_f32_16x16x32_bf16(a, b, c, 0, 0, 0);
}
DEV floatx4 mfma16x16(bf16x4 a, bf16x4 b, floatx4 c) {
    // K=16 bf16 MFMA: operand k = quad*4+j  == S^T C/D row layout (key=quad*4+r)
    return __builtin_amdgcn_mfma_f32_16x16x16bf16_1k(
        __builtin_bit_cast(short4v, a), __builtin_bit_cast(short4v, b), c, 0, 0, 0);
}

// Fragment-linear layouts (element indices), bh = b*12+h:
//  QF/KF: idx = ((bh*64 + t16)*2 + kfi)*512 + (quad*16 + (row&15))*8 + (hd&7)
//  VF:    idx = (((bh*16 + kt)*4 + w)*4 + mg)*256 + (((key>>2)&3)*16 + (hd&15))*4 + (key&3)
// Attention loads become base + lane*16B / lane*8B: perfectly coalesced.

// ---------------- fused prep: x->bf16 | W transpose->bf16 | bias concat ----------------
__global__ __launch_bounds__(256) void k_prep(const float* __restrict__ x,
                                              __bf16* __restrict__ xb,
                                              const float* __restrict__ Wq,
                                              const float* __restrict__ Wk,
                                              const float* __restrict__ Wv,
                                              const float* __restrict__ Wo,
                                              __bf16* __restrict__ wtqkv,
                                              __bf16* __restrict__ wto,
                                              const float* __restrict__ bq,
                                              const float* __restrict__ bk,
                                              const float* __restrict__ bv,
                                              float* __restrict__ bqkv) {
    __shared__ float tile[32][33];
    int bid = blockIdx.x, t = threadIdx.x;
    if (bid < 6144) {                       // x fp32 -> bf16, 4 elem/thread
        int i = (bid * 256 + t) * 4;
        float4 v = *(const float4*)(x + i);
        bf16x4 o;
        o[0] = (__bf16)v.x; o[1] = (__bf16)v.y; o[2] = (__bf16)v.z; o[3] = (__bf16)v.w;
        *(bf16x4*)(xb + i) = o;
    } else if (bid < 8448) {                // W [K,N] -> Wt [N,K] bf16
        int idx = bid - 6144;
        int z = idx / 576, rem = idx % 576;
        int k0 = (rem % 24) * 32, n0 = (rem / 24) * 32;
        const float* W = (z == 0) ? Wq : (z == 1) ? Wk : (z == 2) ? Wv : Wo;
        int tx = t & 31, ty = t >> 5;
#pragma unroll
        for (int p = 0; p < 4; p++)
            tile[ty + 8 * p][tx] = W[(size_t)(k0 + ty + 8 * p) * 768 + n0 + tx];
        __syncthreads();
        __bf16* out = (z < 3) ? (wtqkv + (size_t)z * 768 * 768) : wto;
#pragma unroll
        for (int p = 0; p < 4; p++)
            out[(size_t)(n0 + ty + 8 * p) * 768 + k0 + tx] = (__bf16)tile[tx][ty + 8 * p];
    } else {                                // bias concat
        int i = (bid - 8448) * 256 + t;
        if (i < 768) bqkv[i] = bq[i];
        else if (i < 1536) bqkv[i] = bk[i - 768];
        else bqkv[i] = bv[i - 1536];
    }
}

// ---------------- QKV GEMM: 3-slot LDS ring, depth-2 prefetch, counted vmcnt ----------------
// BM=256, BN=128, BK=64. 8 waves (4M x 2N), per-wave 64x64 output, acc[4][4].
// Tile t computed from slot t%3 while tile t+2 streams into slot (t+2)%3: reader
// and writer slots always distinct -> ONE barrier per K-tile, vmcnt never drains
// to 0 in steady state. Exactly 6 global_load_lds per tile (A:4, B:2), so at each
// tile boundary "s_waitcnt vmcnt(6)" proves tile t+1 landed (in-order retire).
// waitcnt+s_barrier fused in one asm block: no hoist window. Fully unrolled: slot
// indices compile-time, no scratch vmem ops to corrupt the vmcnt count.
// LDS rows are 8 chunks of 16B; chunk XOR-swizzled with (row&7) (2-way = free).
__global__ __launch_bounds__(512) void k_qkv(const __bf16* __restrict__ A,
                                             const __bf16* __restrict__ Bt,
                                             const float* __restrict__ bias,
                                             __bf16* __restrict__ qfb,
                                             __bf16* __restrict__ kfb,
                                             __bf16* __restrict__ vfb) {
    constexpr int SLOT = 24576;            // elems: As 256*64 + Bs 128*64
    __shared__ __align__(16) __bf16 lds[3 * SLOT];   // 144 KB
    int t = threadIdx.x, lane = t & 63, w = t >> 6;
    int quad = lane >> 4, n16 = lane & 15;
    int wm = w >> 1, wn = w & 1;           // 4M x 2N wave grid
    int m0 = blockIdx.x * 256, n0 = blockIdx.y * 128;
    floatx4 acc[4][4] = {};

    // stage one kfi-phase worth of tile (k0) into slot base: A insts {2p,2p+1}, B inst {p}
    auto stage_part = [&](__bf16* slot, int k0, int p) {
        __bf16* As_ = slot;
        __bf16* Bs_ = slot + 16384;
#pragma unroll
        for (int i = 2 * p; i < 2 * p + 2; i++) {
            int off = t + i * 512;         // 0..2047 -> row 0..255
            int row = off >> 3, pc = off & 7;
            int c = pc ^ (row & 7);
            async_copy16(&As_[row * 64 + pc * 8],
                         &A[(size_t)(m0 + row) * 768 + k0 + c * 8]);
        }
        {
            int off = t + p * 512;         // 0..1023 -> row 0..127
            int row = off >> 3, pc = off & 7;
            int c = pc ^ (row & 7);
            async_copy16(&Bs_[row * 64 + pc * 8],
                         &Bt[(size_t)(n0 + row) * 768 + k0 + c * 8]);
        }
    };

    // prologue: tiles 0,1 in flight; wait tile 0 (6 newest may remain outstanding)
    stage_part(lds, 0, 0);
    stage_part(lds, 0, 1);
    stage_part(lds + SLOT, 64, 0);
    stage_part(lds + SLOT, 64, 1);
    asm volatile("s_waitcnt vmcnt(6)\n\ts_barrier" ::: "memory");
    __builtin_amdgcn_sched_barrier(0);

#pragma unroll
    for (int kt = 0; kt < 12; kt++) {
        __bf16* As_ = lds + (kt % 3) * SLOT;
        __bf16* Bs_ = As_ + 16384;
        __bf16* pf = lds + ((kt + 2) % 3) * SLOT;
        int pk0 = (kt + 2) * 64;
        bool do_pf = (kt + 2 < 12);

#pragma unroll
        for (int kfi = 0; kfi < 2; kfi++) {
            if (do_pf) stage_part(pf, pk0, kfi);   // 3 loads in flight per phase
            bf16x8 a[4], bfr[4];
#pragma unroll
            for (int rt = 0; rt < 4; rt++) {
                int row = wm * 64 + rt * 16 + n16;
                a[rt] = *(const bf16x8*)&As_[row * 64 + ((quad + 4 * kfi) ^ (row & 7)) * 8];
            }
#pragma unroll
            for (int ct = 0; ct < 4; ct++) {
                int row = wn * 64 + ct * 16 + n16;
                bfr[ct] = *(const bf16x8*)&Bs_[row * 64 + ((quad + 4 * kfi) ^ (row & 7)) * 8];
            }
            __builtin_amdgcn_s_setprio(1);
#pragma unroll
            for (int rt = 0; rt < 4; rt++)
#pragma unroll
                for (int ct = 0; ct < 4; ct++)
                    acc[rt][ct] = mfma16x32(a[rt], bfr[ct], acc[rt][ct]);
            __builtin_amdgcn_s_setprio(0);
        }

        if (kt < 11) {
            __builtin_amdgcn_sched_barrier(0);
            if (kt < 10) {
                // outstanding = tile kt+2's 6 loads -> tile kt+1 proven landed
                asm volatile("s_waitcnt vmcnt(6)\n\ts_barrier" ::: "memory");
            } else {
                // no tile 12: drain tile 11 fully
                asm volatile("s_waitcnt vmcnt(0)\n\ts_barrier" ::: "memory");
            }
            __builtin_amdgcn_sched_barrier(0);
        }
    }

    // epilogue: C/D layout col=lane&15, row=quad*4+reg. Zone is block-uniform.
    // (verbatim from the proven BN=128 QKV epilogue; wm now spans 0..3 over BM=256)
    if (n0 >= 1536) {
        // V -> VF fragment-linear, b64 stores
#pragma unroll
        for (int ct = 0; ct < 4; ct++) {
            int col = n0 + wn * 64 + ct * 16 + n16;
            float bs = bias[col];
            int cz = col - 1536;
            int hh = cz >> 6, hd = cz & 63;
            int mg = hd >> 4, l16 = hd & 15;
#pragma unroll
            for (int rt = 0; rt < 4; rt++) {
                int row0 = m0 + wm * 64 + rt * 16 + quad * 4;
                int bb = row0 >> 10, key = row0 & 1023;
                int ktv = key >> 6, wv = (key >> 4) & 3, qd = (key >> 2) & 3;
                bf16x4 pk;
#pragma unroll
                for (int r = 0; r < 4; r++) pk[r] = (__bf16)(acc[rt][ct][r] + bs);
                size_t idx = ((((size_t)(bb * 12 + hh) * 16 + ktv) * 4 + wv) * 4 + mg) * 256
                             + (size_t)(qd * 16 + l16) * 4;
                *(bf16x4*)&vfb[idx] = pk;
            }
        }
    } else {
        __bf16* dst = (n0 < 768) ? qfb : kfb;
        float mult = (n0 < 768) ? CS : 1.0f;
        int cofs = (n0 < 768) ? 0 : 768;
#pragma unroll
        for (int ct = 0; ct < 4; ct++) {
            int col = n0 + wn * 64 + ct * 16 + n16;
            float bs = bias[col];
            int cz = col - cofs;
            int hh = cz >> 6, hd = cz & 63;
            int kfi = hd >> 5, qd2 = (hd >> 3) & 3, j = hd & 7;
#pragma unroll
            for (int rt = 0; rt < 4; rt++) {
                int row0 = m0 + wm * 64 + rt * 16 + quad * 4;
                int bb = row0 >> 10, q = row0 & 1023;
                int t16 = q >> 4, nn = q & 15;  // q%4==0 -> nn+r stays <16
                size_t idx = (((size_t)(bb * 12 + hh) * 64 + t16) * 2 + kfi) * 512
                             + (size_t)(qd2 * 16 + nn) * 8 + j;
#pragma unroll
                for (int r = 0; r < 4; r++)
                    dst[idx + (size_t)r * 8] = (__bf16)((acc[rt][ct][r] + bs) * mult);
            }
        }
    }
}

// ---------------- GEMM (O-projection): R6-proven 2-barrier structure ----------------
// BM=128, BN templated (64 for O-proj grid shape). 4 waves, 4xCT acc of 16x16x32 MFMA.
// LDS rows are 8 chunks of 16B; chunk XOR-swizzled with (row&7).
template <typename OutT, bool QKV, int BN>
__global__ __launch_bounds__(256) void k_gemm(const __bf16* __restrict__ A,
                                              const __bf16* __restrict__ Bt,
                                              const float* __restrict__ bias,
                                              OutT* __restrict__ C, int Nn,
                                              __bf16* __restrict__ qfb,
                                              __bf16* __restrict__ kfb,
                                              __bf16* __restrict__ vfb) {
    constexpr int CT = BN / 32;        // col-tiles per wave (64->2)
    constexpr int NBI = BN / 32;       // B staging insts/thread
    __shared__ __align__(16) __bf16 As[128 * 64];
    __shared__ __align__(16) __bf16 Bs[BN * 64];
    int t = threadIdx.x, lane = t & 63, w = t >> 6;
    int quad = lane >> 4, n16 = lane & 15;
    int wm = w & 1, wn = w >> 1;
    int m0 = blockIdx.x * 128, n0 = blockIdx.y * BN;
    floatx4 acc[4][CT] = {};

    for (int k0 = 0; k0 < 768; k0 += 64) {
        __syncthreads();
#pragma unroll
        for (int i = 0; i < 4; i++) {  // stage A tile 128x64 (16KB)
            int off = t + i * 256;
            int row = off >> 3, pc = off & 7;
            int c = pc ^ (row & 7);
            async_copy16(&As[row * 64 + pc * 8],
                         &A[(size_t)(m0 + row) * 768 + k0 + c * 8]);
        }
#pragma unroll
        for (int i = 0; i < NBI; i++) {  // stage B tile BNx64
            int off = t + i * 256;
            int row = off >> 3, pc = off & 7;
            int c = pc ^ (row & 7);
            async_copy16(&Bs[row * 64 + pc * 8],
                         &Bt[(size_t)(n0 + row) * 768 + k0 + c * 8]);
        }
        __builtin_amdgcn_s_waitcnt(0);  // drain global_load_lds before barrier
        __syncthreads();
#pragma unroll
        for (int kfi = 0; kfi < 2; kfi++) {
            bf16x8 a[4], bfr[CT];
#pragma unroll
            for (int rt = 0; rt < 4; rt++) {
                int row = wm * 64 + rt * 16 + n16;
                a[rt] = *(const bf16x8*)&As[row * 64 + ((quad + 4 * kfi) ^ (row & 7)) * 8];
            }
#pragma unroll
            for (int ct = 0; ct < CT; ct++) {
                int row = wn * (BN / 2) + ct * 16 + n16;
                bfr[ct] = *(const bf16x8*)&Bs[row * 64 + ((quad + 4 * kfi) ^ (row & 7)) * 8];
            }
#pragma unroll
            for (int rt = 0; rt < 4; rt++)
#pragma unroll
                for (int ct = 0; ct < CT; ct++)
                    acc[rt][ct] = mfma16x32(a[rt], bfr[ct], acc[rt][ct]);
        }
    }

    // epilogue: C/D layout col=lane&15, row=quad*4+reg.
    if (QKV) {
        // (unused instantiation path removed from launch; kept for template validity)
    } else {
#pragma unroll
        for (int ct = 0; ct < CT; ct++) {
            int col = n0 + wn * (BN / 2) + ct * 16 + n16;
            float bs = bias[col];
#pragma unroll
            for (int rt = 0; rt < 4; rt++) {
#pragma unroll
                for (int r = 0; r < 4; r++) {
                    int row = m0 + wm * 64 + rt * 16 + quad * 4 + r;
                    C[(size_t)row * Nn + col] = (OutT)(acc[rt][ct][r] + bs);
                }
            }
        }
    }
}

// ---------------- flash attention: barrier-free loop, fragment-linear loads ----------------
// Block = 32 qrows of one (b,h); wave w owns keys [kt*64+w*16, +16) each iter.
// Q/K/V pre-stored in MFMA-fragment order -> every load is base + lane*(16|8)B,
// perfectly coalesced, L2-resident (XCD-pinned). Explicit depth-1 register
// double-buffer keeps next iter's loads in flight during compute.
// S^T = K_sub·Q^T (16x16x32); P feeds PV register-direct via K=16 MFMA.
// Quiet softmax exact identity: out = p / (max(p) + sum(p)), p = 2^(s_scaled).
__global__ __launch_bounds__(256) void k_attn(const __bf16* __restrict__ QF,
                                              const __bf16* __restrict__ KF,
                                              const __bf16* __restrict__ VF,
                                              __bf16* __restrict__ ctx) {
    __shared__ __align__(16) unsigned char smem[18432];
    float* buf0 = (float*)smem;                    // [32][68] fp32, 8.7KB
    float* buf1 = (float*)(smem + 8704);           // 8.7KB
    float* Lsum = (float*)(smem + 17408);          // [4][32]
    float* Pmax = (float*)(smem + 17920);          // [4][32]

    int t = threadIdx.x, lane = t & 63, w = t >> 6;
    int quad = lane >> 4, n16 = lane & 15;
    // XCD-pinned swizzle: batch = id&7 pins each batch's K/V to one XCD's L2
    int id = blockIdx.x;
    int bB = id & 7;
    int seq = id >> 3;
    int h = seq % 12;
    int qt = seq / 12;
    int q0 = qt * 32;
    int bh = bB * NH + h;

    // Q fragments: coalesced frag-linear loads
    bf16x8 qf[2][2];
    {
        const __bf16* qp = QF + (size_t)(bh * 64 + qt * 2) * 1024 + lane * 8;
#pragma unroll
        for (int ng = 0; ng < 2; ng++)
#pragma unroll
            for (int kfi = 0; kfi < 2; kfi++)
                qf[ng][kfi] = *(const bf16x8*)(qp + (ng * 2 + kfi) * 512);
    }
    const __bf16* kp = KF + (size_t)(bh * 64 + w) * 1024 + lane * 8;
    const __bf16* vp = VF + ((size_t)bh * 16 * 4 + w) * 1024 + lane * 4;

    floatx4 acc[4][2] = {};               // O^T partial: [mg=hd group][ng=qrow group]
    float rs[2] = {0.f, 0.f};             // sum(p) per qrow ng*16+n16, wave's keys
    float pm[2] = {0.f, 0.f};             // max(p) likewise

    auto compute = [&](bf16x8 (&kf)[2], bf16x4 (&vf)[4]) {
        floatx4 s[2] = {};
#pragma unroll
        for (int ng = 0; ng < 2; ng++)
#pragma unroll
            for (int kfi = 0; kfi < 2; kfi++)
                s[ng] = mfma16x32(kf[kfi], qf[ng][kfi], s[ng]);
        bf16x4 pb[2];
#pragma unroll
        for (int ng = 0; ng < 2; ng++) {
#pragma unroll
            for (int r = 0; r < 4; r++) {
                float p = __builtin_amdgcn_exp2f(s[ng][r]);
                rs[ng] += p;
                pm[ng] = fmaxf(pm[ng], p);
                pb[ng][r] = (__bf16)p;
            }
        }
#pragma unroll
        for (int mg = 0; mg < 4; mg++)
#pragma unroll
            for (int ng = 0; ng < 2; ng++)
                acc[mg][ng] = mfma16x16(vf[mg], pb[ng], acc[mg][ng]);
    };

    // software pipeline, depth 1, two named register sets
    bf16x8 kf0[2], kf1[2];
    bf16x4 vf0[4], vf1[4];
    kf0[0] = *(const bf16x8*)kp;
    kf0[1] = *(const bf16x8*)(kp + 512);
#pragma unroll
    for (int mg = 0; mg < 4; mg++) vf0[mg] = *(const bf16x4*)(vp + mg * 256);
    kp += 4096; vp += 4096;

    for (int kt = 0; kt < 16; kt += 2) {
        kf1[0] = *(const bf16x8*)kp;
        kf1[1] = *(const bf16x8*)(kp + 512);
#pragma unroll
        for (int mg = 0; mg < 4; mg++) vf1[mg] = *(const bf16x4*)(vp + mg * 256);
        kp += 4096; vp += 4096;
        compute(kf0, vf0);
        if (kt < 14) {
            kf0[0] = *(const bf16x8*)kp;
            kf0[1] = *(const bf16x8*)(kp + 512);
#pragma unroll
            for (int mg = 0; mg < 4; mg++) vf0[mg] = *(const bf16x4*)(vp + mg * 256);
            kp += 4096; vp += 4096;
        }
        compute(kf1, vf1);
    }

    // reduce sum/max across quads (quads held disjoint keys)
#pragma unroll
    for (int ng = 0; ng < 2; ng++) {
        rs[ng] += __shfl_xor(rs[ng], 16);
        rs[ng] += __shfl_xor(rs[ng], 32);
        pm[ng] = fmaxf(pm[ng], __shfl_xor(pm[ng], 16));
        pm[ng] = fmaxf(pm[ng], __shfl_xor(pm[ng], 32));
    }
    if (quad < 2) {
        Lsum[w * 32 + quad * 16 + n16] = quad ? rs[1] : rs[0];
        Pmax[w * 32 + quad * 16 + n16] = quad ? pm[1] : pm[0];
    }
    __syncthreads();

    // cross-wave O reduction: b128 stores, [qrow][hd] stride 68 (2-way = free)
    float* mybuf = (w & 1) ? buf1 : buf0;
    if (w < 2) {
#pragma unroll
        for (int mg = 0; mg < 4; mg++)
#pragma unroll
            for (int ng = 0; ng < 2; ng++)
                *(floatx4*)&mybuf[(ng * 16 + n16) * 68 + mg * 16 + quad * 4] = acc[mg][ng];
    }
    __syncthreads();
    if (w >= 2) {
#pragma unroll
        for (int mg = 0; mg < 4; mg++)
#pragma unroll
            for (int ng = 0; ng < 2; ng++) {
                float* p = &mybuf[(ng * 16 + n16) * 68 + mg * 16 + quad * 4];
                floatx4 cur = *(const floatx4*)p;
                *(floatx4*)p = cur + acc[mg][ng];
            }
    }
    __syncthreads();

    // final: out[qrow][hd] = (buf0+buf1) / (pmax + l); coalesced 16B stores
    int qrow = t >> 3;
    int hh = (t & 7) * 8;
    float l = Lsum[qrow] + Lsum[32 + qrow] + Lsum[64 + qrow] + Lsum[96 + qrow];
    float pmx = fmaxf(fmaxf(Pmax[qrow], Pmax[32 + qrow]),
                      fmaxf(Pmax[64 + qrow], Pmax[96 + qrow]));
    float invd = 1.f / (pmx + l);
    floatx4 v0 = *(const floatx4*)&buf0[qrow * 68 + hh];
    floatx4 v1 = *(const floatx4*)&buf0[qrow * 68 + hh + 4];
    floatx4 u0 = *(const floatx4*)&buf1[qrow * 68 + hh];
    floatx4 u1 = *(const floatx4*)&buf1[qrow * 68 + hh + 4];
    bf16x8 o;
#pragma unroll
    for (int j = 0; j < 4; j++) o[j] = (__bf16)((v0[j] + u0[j]) * invd);
#pragma unroll
    for (int j = 0; j < 4; j++) o[j + 4] = (__bf16)((v1[j] + u1[j]) * invd);
    __bf16* dst = ctx + (size_t)(bB * NSEQ + q0 + qrow) * DMODEL + h * 64 + hh;
    *(bf16x8*)dst = o;
}

extern "C" void kernel_launch(void* const* d_in, const int* in_sizes, int n_in,
                              void* d_out, int out_size, void* d_ws, size_t ws_size,
                              hipStream_t stream) {
    (void)in_sizes; (void)n_in; (void)out_size;
    const float* x  = (const float*)d_in[0];
    const float* Wq = (const float*)d_in[1];
    const float* bq = (const float*)d_in[2];
    const float* Wk = (const float*)d_in[3];
    const float* bk = (const float*)d_in[4];
    const float* Wv = (const float*)d_in[5];
    const float* bv = (const float*)d_in[6];
    const float* Wo = (const float*)d_in[7];
    const float* bo = (const float*)d_in[8];
    float* out = (float*)d_out;

    char* ws = (char*)d_ws;
    size_t off = 0;
    auto alloc = [&](size_t bytes) {
        void* p = ws + off;
        off += (bytes + 255) & ~(size_t)255;
        return p;
    };
    __bf16* xb    = (__bf16*)alloc((size_t)MTOK * DMODEL * 2);   // 12.6 MB (reused as ctx)
    __bf16* wtqkv = (__bf16*)alloc((size_t)NQKV * DMODEL * 2);   // 3.5 MB
    __bf16* wto   = (__bf16*)alloc((size_t)DMODEL * DMODEL * 2); // 1.2 MB
    float*  bqkv  = (float*)alloc((size_t)NQKV * 4);
    __bf16* qfb   = (__bf16*)alloc((size_t)MTOK * DMODEL * 2);   // 12.6 MB frag-linear Q
    __bf16* kfb   = (__bf16*)alloc((size_t)MTOK * DMODEL * 2);   // 12.6 MB frag-linear K
    __bf16* vfb   = (__bf16*)alloc((size_t)MTOK * DMODEL * 2);   // 12.6 MB frag-linear V
    if (off > ws_size) return;  // workspace too small -> visible failure
    __bf16* ctx = xb;  // xb dead after QKV GEMM

    k_prep<<<dim3(8457), dim3(256), 0, stream>>>(x, xb, Wq, Wk, Wv, Wo, wtqkv, wto,
                                                 bq, bk, bv, bqkv);
    k_qkv<<<dim3(32, 18), dim3(512), 0, stream>>>(xb, wtqkv, bqkv, qfb, kfb, vfb);
    k_attn<<<dim3(3072), dim3(256), 0, stream>>>(qfb, kfb, vfb, ctx);
    k_gemm<float, false, 64><<<dim3(64, 12), dim3(256), 0, stream>>>(
        ctx, wto, bo, out, DMODEL, nullptr, nullptr, nullptr);
}

// Round 2
// 182.527 us; speedup vs baseline: 1.1383x; 1.1281x over previous
//
#include <hip/hip_runtime.h>
#include <cstdint>

#define DEV __device__ __forceinline__

typedef __bf16 bf16x4 __attribute__((ext_vector_type(4)));
typedef __bf16 bf16x8 __attribute__((ext_vector_type(8)));
typedef float  floatx4 __attribute__((ext_vector_type(4)));
typedef float  floatx16 __attribute__((ext_vector_type(16)));
typedef unsigned uint4v __attribute__((ext_vector_type(4)));

constexpr int BB = 8, NSEQ = 1024, DMODEL = 768, NH = 12, HD = 64;
constexpr int MTOK = BB * NSEQ;   // 8192 tokens
constexpr int NQKV = 3 * DMODEL;  // 2304
constexpr float CS = 0.18033688011112042f;  // (1/sqrt(64)) * log2(e), folded into Q

DEV void async_copy16(void* lds, const void* g) {
    // global -> LDS direct copy, 16B/lane. LDS dest must be wave-base + lane*16.
    __builtin_amdgcn_global_load_lds(
        (__attribute__((address_space(1))) void*)(const_cast<void*>(g)),
        (__attribute__((address_space(3))) void*)lds,
        16, 0, 0);
}

DEV floatx4 mfma16x32(bf16x8 a, bf16x8 b, floatx4 c) {
    return __builtin_amdgcn_mfma_f32_16x16x32_bf16(a, b, c, 0, 0, 0);
}
DEV floatx16 mfma32x16(bf16x8 a, bf16x8 b, floatx16 c) {
    return __builtin_amdgcn_mfma_f32_32x32x16_bf16(a, b, c, 0, 0, 0);
}
DEV unsigned cvtpk(float a, float b) {
    unsigned r;
    asm("v_cvt_pk_bf16_f32 %0, %1, %2" : "=v"(r) : "v"(a), "v"(b));
    return r;
}
DEV void swap32(unsigned& x, unsigned& y) {
    // x' = {x[0:31], y[0:31]}, y' = {x[32:63], y[32:63]} (lane-half exchange)
    asm("v_permlane32_swap_b32 %0, %1" : "+v"(x), "+v"(y));
}

// 32x32x16 fragment-linear layouts (element indices), bh = b*12+h, b5 = lane>>5, l5 = lane&31:
//  QF (B-op): idx = ((bh*32 + qt)*4 + kfi)*512 + lane*8 + j
//             = Q[qrow = qt*32 + l5][hd = kfi*16 + b5*8 + j] * CS (+bias)
//  KF (A-op): idx = (((bh*8 + i)*4 + w)*4 + kfi)*512 + lane*8 + j
//             = K[key = i*128 + w*32 + l5][hd = kfi*16 + b5*8 + j]
//  VF (A-op): idx = ((((bh*8 + i)*4 + w)*2 + kc)*2 + mg)*512 + lane*8 + j
//             = V[key = i*128 + w*32 + kc*16 + b5*8 + j][hd = mg*32 + l5]
// All attention loads: base + lane*16B, perfectly coalesced, L2-resident (XCD-pinned).

// ---------------- fused prep: x->bf16 | W transpose->bf16 | bias concat ----------------
__global__ __launch_bounds__(256) void k_prep(const float* __restrict__ x,
                                              __bf16* __restrict__ xb,
                                              const float* __restrict__ Wq,
                                              const float* __restrict__ Wk,
                                              const float* __restrict__ Wv,
                                              const float* __restrict__ Wo,
                                              __bf16* __restrict__ wtqkv,
                                              __bf16* __restrict__ wto,
                                              const float* __restrict__ bq,
                                              const float* __restrict__ bk,
                                              const float* __restrict__ bv,
                                              float* __restrict__ bqkv) {
    __shared__ float tile[32][33];
    int bid = blockIdx.x, t = threadIdx.x;
    if (bid < 6144) {                       // x fp32 -> bf16, 4 elem/thread
        int i = (bid * 256 + t) * 4;
        float4 v = *(const float4*)(x + i);
        bf16x4 o;
        o[0] = (__bf16)v.x; o[1] = (__bf16)v.y; o[2] = (__bf16)v.z; o[3] = (__bf16)v.w;
        *(bf16x4*)(xb + i) = o;
    } else if (bid < 8448) {                // W [K,N] -> Wt [N,K] bf16
        int idx = bid - 6144;
        int z = idx / 576, rem = idx % 576;
        int k0 = (rem % 24) * 32, n0 = (rem / 24) * 32;
        const float* W = (z == 0) ? Wq : (z == 1) ? Wk : (z == 2) ? Wv : Wo;
        int tx = t & 31, ty = t >> 5;
#pragma unroll
        for (int p = 0; p < 4; p++)
            tile[ty + 8 * p][tx] = W[(size_t)(k0 + ty + 8 * p) * 768 + n0 + tx];
        __syncthreads();
        __bf16* out = (z < 3) ? (wtqkv + (size_t)z * 768 * 768) : wto;
#pragma unroll
        for (int p = 0; p < 4; p++)
            out[(size_t)(n0 + ty + 8 * p) * 768 + k0 + tx] = (__bf16)tile[tx][ty + 8 * p];
    } else {                                // bias concat
        int i = (bid - 8448) * 256 + t;
        if (i < 768) bqkv[i] = bq[i];
        else if (i < 1536) bqkv[i] = bk[i - 768];
        else bqkv[i] = bv[i - 1536];
    }
}

// ---------------- QKV GEMM: 3-slot LDS ring, depth-2 prefetch, counted vmcnt ----------------
// (main loop proven R0; epilogue rewritten for 32x32 fragment layouts)
__global__ __launch_bounds__(512) void k_qkv(const __bf16* __restrict__ A,
                                             const __bf16* __restrict__ Bt,
                                             const float* __restrict__ bias,
                                             __bf16* __restrict__ qfb,
                                             __bf16* __restrict__ kfb,
                                             __bf16* __restrict__ vfb) {
    constexpr int SLOT = 24576;            // elems: As 256*64 + Bs 128*64
    __shared__ __align__(16) __bf16 lds[3 * SLOT];   // 144 KB
    int t = threadIdx.x, lane = t & 63, w = t >> 6;
    int quad = lane >> 4, n16 = lane & 15;
    int wm = w >> 1, wn = w & 1;           // 4M x 2N wave grid
    int m0 = blockIdx.x * 256, n0 = blockIdx.y * 128;
    floatx4 acc[4][4] = {};

    auto stage_part = [&](__bf16* slot, int k0, int p) {
        __bf16* As_ = slot;
        __bf16* Bs_ = slot + 16384;
#pragma unroll
        for (int i = 2 * p; i < 2 * p + 2; i++) {
            int off = t + i * 512;         // 0..2047 -> row 0..255
            int row = off >> 3, pc = off & 7;
            int c = pc ^ (row & 7);
            async_copy16(&As_[row * 64 + pc * 8],
                         &A[(size_t)(m0 + row) * 768 + k0 + c * 8]);
        }
        {
            int off = t + p * 512;         // 0..1023 -> row 0..127
            int row = off >> 3, pc = off & 7;
            int c = pc ^ (row & 7);
            async_copy16(&Bs_[row * 64 + pc * 8],
                         &Bt[(size_t)(n0 + row) * 768 + k0 + c * 8]);
        }
    };

    stage_part(lds, 0, 0);
    stage_part(lds, 0, 1);
    stage_part(lds + SLOT, 64, 0);
    stage_part(lds + SLOT, 64, 1);
    asm volatile("s_waitcnt vmcnt(6)\n\ts_barrier" ::: "memory");
    __builtin_amdgcn_sched_barrier(0);

#pragma unroll
    for (int kt = 0; kt < 12; kt++) {
        __bf16* As_ = lds + (kt % 3) * SLOT;
        __bf16* Bs_ = As_ + 16384;
        __bf16* pf = lds + ((kt + 2) % 3) * SLOT;
        int pk0 = (kt + 2) * 64;
        bool do_pf = (kt + 2 < 12);

#pragma unroll
        for (int kfi = 0; kfi < 2; kfi++) {
            if (do_pf) stage_part(pf, pk0, kfi);
            bf16x8 a[4], bfr[4];
#pragma unroll
            for (int rt = 0; rt < 4; rt++) {
                int row = wm * 64 + rt * 16 + n16;
                a[rt] = *(const bf16x8*)&As_[row * 64 + ((quad + 4 * kfi) ^ (row & 7)) * 8];
            }
#pragma unroll
            for (int ct = 0; ct < 4; ct++) {
                int row = wn * 64 + ct * 16 + n16;
                bfr[ct] = *(const bf16x8*)&Bs_[row * 64 + ((quad + 4 * kfi) ^ (row & 7)) * 8];
            }
            __builtin_amdgcn_s_setprio(1);
#pragma unroll
            for (int rt = 0; rt < 4; rt++)
#pragma unroll
                for (int ct = 0; ct < 4; ct++)
                    acc[rt][ct] = mfma16x32(a[rt], bfr[ct], acc[rt][ct]);
            __builtin_amdgcn_s_setprio(0);
        }

        if (kt < 11) {
            __builtin_amdgcn_sched_barrier(0);
            if (kt < 10) {
                asm volatile("s_waitcnt vmcnt(6)\n\ts_barrier" ::: "memory");
            } else {
                asm volatile("s_waitcnt vmcnt(0)\n\ts_barrier" ::: "memory");
            }
            __builtin_amdgcn_sched_barrier(0);
        }
    }

    // epilogue: C/D layout col=lane&15, row=quad*4+reg. Zone is block-uniform.
    if (n0 >= 1536) {
        // V zone -> VF (A-operand of 32x32x16 PV)
#pragma unroll
        for (int ct = 0; ct < 4; ct++) {
            int col = n0 + wn * 64 + ct * 16 + n16;
            float bs = bias[col];
            int cz = col - 1536;
            int hh = cz >> 6, hd = cz & 63;
            int mg = hd >> 5, l5v = hd & 31;
#pragma unroll
            for (int rt = 0; rt < 4; rt++) {
                int row0 = m0 + wm * 64 + rt * 16 + quad * 4;
                int bb = row0 >> 10, key = row0 & 1023;
                int iw = key >> 7, w_ = (key >> 5) & 3, kc = (key >> 4) & 1;
                int b5v = (key >> 3) & 1, j0 = key & 7;  // +r stays in octet (quad*4 base)
                bf16x4 pk;
#pragma unroll
                for (int r = 0; r < 4; r++) pk[r] = (__bf16)(acc[rt][ct][r] + bs);
                size_t idx = (((((size_t)(bb * 12 + hh) * 8 + iw) * 4 + w_) * 2 + kc) * 2 + mg) * 512
                             + (size_t)(b5v * 32 + l5v) * 8 + j0;
                *(bf16x4*)&vfb[idx] = pk;
            }
        }
    } else {
        __bf16* dst = (n0 < 768) ? qfb : kfb;
        float mult = (n0 < 768) ? CS : 1.0f;
        bool isQ = (n0 < 768);
        int cofs = isQ ? 0 : 768;
#pragma unroll
        for (int ct = 0; ct < 4; ct++) {
            int col = n0 + wn * 64 + ct * 16 + n16;
            float bs = bias[col];
            int cz = col - cofs;
            int hh = cz >> 6, hd = cz & 63;
            int kfi = hd >> 4, b5v = (hd >> 3) & 1, j = hd & 7;
#pragma unroll
            for (int rt = 0; rt < 4; rt++) {
                int row0 = m0 + wm * 64 + rt * 16 + quad * 4;
                int bb = row0 >> 10, q10 = row0 & 1023;
                size_t idx;
                if (isQ) {
                    int qt = q10 >> 5, l5v = q10 & 31;  // l5v+r no carry (quad*4 base)
                    idx = (((size_t)(bb * 12 + hh) * 32 + qt) * 4 + kfi) * 512
                          + (size_t)(b5v * 32 + l5v) * 8 + j;
                } else {
                    int iw = q10 >> 7, w_ = (q10 >> 5) & 3, l5v = q10 & 31;
                    idx = ((((size_t)(bb * 12 + hh) * 8 + iw) * 4 + w_) * 4 + kfi) * 512
                          + (size_t)(b5v * 32 + l5v) * 8 + j;
                }
#pragma unroll
                for (int r = 0; r < 4; r++)
                    dst[idx + (size_t)r * 8] = (__bf16)((acc[rt][ct][r] + bs) * mult);
            }
        }
    }
}

// ---------------- GEMM (O-projection): R6-proven 2-barrier structure ----------------
template <typename OutT, int BN>
__global__ __launch_bounds__(256) void k_gemm(const __bf16* __restrict__ A,
                                              const __bf16* __restrict__ Bt,
                                              const float* __restrict__ bias,
                                              OutT* __restrict__ C, int Nn) {
    constexpr int CT = BN / 32;
    constexpr int NBI = BN / 32;
    __shared__ __align__(16) __bf16 As[128 * 64];
    __shared__ __align__(16) __bf16 Bs[BN * 64];
    int t = threadIdx.x, lane = t & 63, w = t >> 6;
    int quad = lane >> 4, n16 = lane & 15;
    int wm = w & 1, wn = w >> 1;
    int m0 = blockIdx.x * 128, n0 = blockIdx.y * BN;
    floatx4 acc[4][CT] = {};

    for (int k0 = 0; k0 < 768; k0 += 64) {
        __syncthreads();
#pragma unroll
        for (int i = 0; i < 4; i++) {
            int off = t + i * 256;
            int row = off >> 3, pc = off & 7;
            int c = pc ^ (row & 7);
            async_copy16(&As[row * 64 + pc * 8],
                         &A[(size_t)(m0 + row) * 768 + k0 + c * 8]);
        }
#pragma unroll
        for (int i = 0; i < NBI; i++) {
            int off = t + i * 256;
            int row = off >> 3, pc = off & 7;
            int c = pc ^ (row & 7);
            async_copy16(&Bs[row * 64 + pc * 8],
                         &Bt[(size_t)(n0 + row) * 768 + k0 + c * 8]);
        }
        __builtin_amdgcn_s_waitcnt(0);
        __syncthreads();
#pragma unroll
        for (int kfi = 0; kfi < 2; kfi++) {
            bf16x8 a[4], bfr[CT];
#pragma unroll
            for (int rt = 0; rt < 4; rt++) {
                int row = wm * 64 + rt * 16 + n16;
                a[rt] = *(const bf16x8*)&As[row * 64 + ((quad + 4 * kfi) ^ (row & 7)) * 8];
            }
#pragma unroll
            for (int ct = 0; ct < CT; ct++) {
                int row = wn * (BN / 2) + ct * 16 + n16;
                bfr[ct] = *(const bf16x8*)&Bs[row * 64 + ((quad + 4 * kfi) ^ (row & 7)) * 8];
            }
#pragma unroll
            for (int rt = 0; rt < 4; rt++)
#pragma unroll
                for (int ct = 0; ct < CT; ct++)
                    acc[rt][ct] = mfma16x32(a[rt], bfr[ct], acc[rt][ct]);
        }
    }

#pragma unroll
    for (int ct = 0; ct < CT; ct++) {
        int col = n0 + wn * (BN / 2) + ct * 16 + n16;
        float bs = bias[col];
#pragma unroll
        for (int rt = 0; rt < 4; rt++) {
#pragma unroll
            for (int r = 0; r < 4; r++) {
                int row = m0 + wm * 64 + rt * 16 + quad * 4 + r;
                C[(size_t)row * Nn + col] = (OutT)(acc[rt][ct][r] + bs);
            }
        }
    }
}

// ---------------- flash attention: 32x32x16 MFMA, swapped QK^T, in-register softmax ----------------
// Block = 32 qrows of one (b,h); 4 waves; wave w owns keys [i*128 + w*32, +32) per iter i=0..7.
// QK^T: S^T[key][qrow] via 4x mfma_32x32x16 (K/Q frag-linear). C/D: col=lane&31=qrow,
// key = 4*(lane>>5) + (reg&3) + 8*(reg>>2): each lane owns 16 keys of ONE qrow -> rs/pm scalar.
// P -> PV B-operand (k = (lane>>5)*8+j) via 8x v_cvt_pk_bf16_f32 + 4x v_permlane32_swap_b32.
// PV: 4x mfma_32x32x16 per 32 keys (full rate; was 16x K=16 half-rate).
// Quiet softmax exact identity: out = p / (max(p) + sum(p)), p = 2^(s_scaled).
__global__ __launch_bounds__(256) void k_attn(const __bf16* __restrict__ QF,
                                              const __bf16* __restrict__ KF,
                                              const __bf16* __restrict__ VF,
                                              __bf16* __restrict__ ctx) {
    __shared__ __align__(16) unsigned char smem[18432];
    float* buf0 = (float*)smem;                    // [32][68] fp32, 8.7KB
    float* buf1 = (float*)(smem + 8704);           // 8.7KB
    float* Lsum = (float*)(smem + 17408);          // [4][32]
    float* Pmax = (float*)(smem + 17920);          // [4][32]

    int t = threadIdx.x, lane = t & 63, w = t >> 6;
    int l5 = lane & 31, b5 = lane >> 5;
    // XCD-pinned swizzle: batch = id&7 pins each batch's K/V to one XCD's L2
    int id = blockIdx.x;
    int bB = id & 7;
    int seq = id >> 3;
    int h = seq % 12;
    int qt = seq / 12;                    // 0..31, q-tile of 32 rows
    int q0 = qt * 32;
    int bh = bB * NH + h;

    // Q fragments (B-operand), coalesced frag-linear loads
    bf16x8 qf[4];
    {
        const __bf16* qp = QF + ((size_t)(bh * 32 + qt) * 4) * 512 + lane * 8;
#pragma unroll
        for (int kfi = 0; kfi < 4; kfi++)
            qf[kfi] = *(const bf16x8*)(qp + kfi * 512);
    }
    const __bf16* kp = KF + ((size_t)(bh * 8) * 4 + w) * 2048 + lane * 8;
    const __bf16* vp = VF + ((size_t)(bh * 8) * 4 + w) * 2048 + lane * 8;

    floatx16 acc[2] = {};                 // O^T: [mg]; D row=hd_local, col=qrow
    float rs = 0.f, pm = 0.f;

    auto compute = [&](bf16x8 (&kf)[4], bf16x8 (&vf)[4]) {
        floatx16 s = {};
#pragma unroll
        for (int kfi = 0; kfi < 4; kfi++)
            s = mfma32x16(kf[kfi], qf[kfi], s);
        float p[16];
#pragma unroll
        for (int r = 0; r < 16; r++) {
            p[r] = __builtin_amdgcn_exp2f(s[r]);
            rs += p[r];
            pm = fmaxf(pm, p[r]);
        }
        // kc0 (keys 0..15): words {x0,x1,y0,y1}; kc1 (keys 16..31): {x2,x3,y2,y3}
        unsigned x0 = cvtpk(p[0], p[1]),   y0 = cvtpk(p[4], p[5]);
        unsigned x1 = cvtpk(p[2], p[3]),   y1 = cvtpk(p[6], p[7]);
        unsigned x2 = cvtpk(p[8], p[9]),   y2 = cvtpk(p[12], p[13]);
        unsigned x3 = cvtpk(p[10], p[11]), y3 = cvtpk(p[14], p[15]);
        swap32(x0, y0); swap32(x1, y1); swap32(x2, y2); swap32(x3, y3);
        uint4v pa = {x0, x1, y0, y1};
        uint4v pbv = {x2, x3, y2, y3};
        bf16x8 P0 = __builtin_bit_cast(bf16x8, pa);
        bf16x8 P1 = __builtin_bit_cast(bf16x8, pbv);
        acc[0] = mfma32x16(vf[0], P0, acc[0]);   // kc0, mg0
        acc[1] = mfma32x16(vf[1], P0, acc[1]);   // kc0, mg1
        acc[0] = mfma32x16(vf[2], P1, acc[0]);   // kc1, mg0
        acc[1] = mfma32x16(vf[3], P1, acc[1]);   // kc1, mg1
    };

    // software pipeline: K double-buffered (depth 1), V loaded at chunk start (used late in PV)
    bf16x8 ka[4], kb[4], vv[4];
#pragma unroll
    for (int f = 0; f < 4; f++) ka[f] = *(const bf16x8*)(kp + f * 512);
    kp += 8192;

    for (int i = 0; i < 8; i += 2) {
#pragma unroll
        for (int f = 0; f < 4; f++) kb[f] = *(const bf16x8*)(kp + f * 512);
        kp += 8192;
#pragma unroll
        for (int f = 0; f < 4; f++) vv[f] = *(const bf16x8*)(vp + f * 512);
        vp += 8192;
        compute(ka, vv);
        if (i < 6) {
#pragma unroll
            for (int f = 0; f < 4; f++) ka[f] = *(const bf16x8*)(kp + f * 512);
            kp += 8192;
        }
#pragma unroll
        for (int f = 0; f < 4; f++) vv[f] = *(const bf16x8*)(vp + f * 512);
        vp += 8192;
        compute(kb, vv);
    }

    // rs/pm: lane-halves held disjoint keys of the same qrow -> one half-swap reduce
    rs += __shfl_xor(rs, 32);
    pm = fmaxf(pm, __shfl_xor(pm, 32));
    if (lane < 32) {
        Lsum[w * 32 + lane] = rs;
        Pmax[w * 32 + lane] = pm;
    }

    // cross-wave O reduction: buf[q][hd] stride 68; hd = mg*32 + 4*b5 + 8*rq + e
    float* mybuf = (w & 1) ? buf1 : buf0;
    if (w < 2) {
#pragma unroll
        for (int mg = 0; mg < 2; mg++)
#pragma unroll
            for (int rq = 0; rq < 4; rq++) {
                floatx4 v = {acc[mg][rq * 4 + 0], acc[mg][rq * 4 + 1],
                             acc[mg][rq * 4 + 2], acc[mg][rq * 4 + 3]};
                *(floatx4*)&mybuf[l5 * 68 + mg * 32 + b5 * 4 + rq * 8] = v;
            }
    }
    __syncthreads();
    if (w >= 2) {
#pragma unroll
        for (int mg = 0; mg < 2; mg++)
#pragma unroll
            for (int rq = 0; rq < 4; rq++) {
                float* p = &mybuf[l5 * 68 + mg * 32 + b5 * 4 + rq * 8];
                floatx4 cur = *(const floatx4*)p;
                floatx4 v = {acc[mg][rq * 4 + 0], acc[mg][rq * 4 + 1],
                             acc[mg][rq * 4 + 2], acc[mg][rq * 4 + 3]};
                *(floatx4*)p = cur + v;
            }
    }
    __syncthreads();

    // final: out[qrow][hd] = (buf0+buf1) / (pmax + l); coalesced 16B stores
    int qrow = t >> 3;
    int hh = (t & 7) * 8;
    float l = Lsum[qrow] + Lsum[32 + qrow] + Lsum[64 + qrow] + Lsum[96 + qrow];
    float pmx = fmaxf(fmaxf(Pmax[qrow], Pmax[32 + qrow]),
                      fmaxf(Pmax[64 + qrow], Pmax[96 + qrow]));
    float invd = 1.f / (pmx + l);
    floatx4 v0 = *(const floatx4*)&buf0[qrow * 68 + hh];
    floatx4 v1 = *(const floatx4*)&buf0[qrow * 68 + hh + 4];
    floatx4 u0 = *(const floatx4*)&buf1[qrow * 68 + hh];
    floatx4 u1 = *(const floatx4*)&buf1[qrow * 68 + hh + 4];
    bf16x8 o;
#pragma unroll
    for (int j = 0; j < 4; j++) o[j] = (__bf16)((v0[j] + u0[j]) * invd);
#pragma unroll
    for (int j = 0; j < 4; j++) o[j + 4] = (__bf16)((v1[j] + u1[j]) * invd);
    __bf16* dst = ctx + (size_t)(bB * NSEQ + q0 + qrow) * DMODEL + h * 64 + hh;
    *(bf16x8*)dst = o;
}

extern "C" void kernel_launch(void* const* d_in, const int* in_sizes, int n_in,
                              void* d_out, int out_size, void* d_ws, size_t ws_size,
                              hipStream_t stream) {
    (void)in_sizes; (void)n_in; (void)out_size;
    const float* x  = (const float*)d_in[0];
    const float* Wq = (const float*)d_in[1];
    const float* bq = (const float*)d_in[2];
    const float* Wk = (const float*)d_in[3];
    const float* bk = (const float*)d_in[4];
    const float* Wv = (const float*)d_in[5];
    const float* bv = (const float*)d_in[6];
    const float* Wo = (const float*)d_in[7];
    const float* bo = (const float*)d_in[8];
    float* out = (float*)d_out;

    char* ws = (char*)d_ws;
    size_t off = 0;
    auto alloc = [&](size_t bytes) {
        void* p = ws + off;
        off += (bytes + 255) & ~(size_t)255;
        return p;
    };
    __bf16* xb    = (__bf16*)alloc((size_t)MTOK * DMODEL * 2);   // 12.6 MB (reused as ctx)
    __bf16* wtqkv = (__bf16*)alloc((size_t)NQKV * DMODEL * 2);   // 3.5 MB
    __bf16* wto   = (__bf16*)alloc((size_t)DMODEL * DMODEL * 2); // 1.2 MB
    float*  bqkv  = (float*)alloc((size_t)NQKV * 4);
    __bf16* qfb   = (__bf16*)alloc((size_t)MTOK * DMODEL * 2);   // 12.6 MB frag-linear Q
    __bf16* kfb   = (__bf16*)alloc((size_t)MTOK * DMODEL * 2);   // 12.6 MB frag-linear K
    __bf16* vfb   = (__bf16*)alloc((size_t)MTOK * DMODEL * 2);   // 12.6 MB frag-linear V
    if (off > ws_size) return;  // workspace too small -> visible failure
    __bf16* ctx = xb;  // xb dead after QKV GEMM

    k_prep<<<dim3(8457), dim3(256), 0, stream>>>(x, xb, Wq, Wk, Wv, Wo, wtqkv, wto,
                                                 bq, bk, bv, bqkv);
    k_qkv<<<dim3(32, 18), dim3(512), 0, stream>>>(xb, wtqkv, bqkv, qfb, kfb, vfb);
    k_attn<<<dim3(3072), dim3(256), 0, stream>>>(qfb, kfb, vfb, ctx);
    k_gemm<float, 64><<<dim3(64, 12), dim3(256), 0, stream>>>(
        ctx, wto, bo, out, DMODEL);
}